// Round 1
// baseline (249.466 us; speedup 1.0000x reference)
//
#include <hip/hip_runtime.h>
#include <math.h>

typedef __attribute__((ext_vector_type(8))) __bf16 bf16x8;
typedef __attribute__((ext_vector_type(4))) __bf16 bf16x4;
typedef __attribute__((ext_vector_type(4))) float floatx4;
typedef __attribute__((ext_vector_type(8))) float floatx8;

__device__ __forceinline__ float fast_rcp(float x) { return __builtin_amdgcn_rcpf(x); }
__device__ __forceinline__ float sigmoidf_(float z) { return fast_rcp(1.0f + __expf(-z)); }
__device__ __forceinline__ float fast_tanh(float z) {
    float e = __expf(2.0f * z);
    return 1.0f - 2.0f * fast_rcp(e + 1.0f);
}
__device__ __forceinline__ float leaky(float v) { return fmaxf(v, 0.01f * v); }

// XOR-swizzled byte offset into a [row][128B] LDS tile: kills the 8-way
// bank conflicts the old XSTR=72 (36-dword stride) layout had. Bijective
// within each 8-row stripe; preserves 8B/16B alignment (only bits 4-6 XORed).
__device__ __forceinline__ int swzb(int row, int byteoff) {
    return row * 128 + (byteoff ^ ((row & 7) << 4));
}

// ---- grid fp32 -> bf16 conversion + W1/W2 bf16 transpose into workspace ----
__global__ void convert_grids(const float* __restrict__ g0, const float* __restrict__ g1,
                              const float* __restrict__ w1f, const float* __restrict__ w2f,
                              __bf16* __restrict__ o0, __bf16* __restrict__ o1,
                              __bf16* __restrict__ w1t, __bf16* __restrict__ w2t, int elems) {
    int i = blockIdx.x * blockDim.x + threadIdx.x;
    int nvec = elems >> 2;
    if (i < nvec) {
        float4 v = ((const float4*)g0)[i];
        bf16x4 r = { (__bf16)v.x, (__bf16)v.y, (__bf16)v.z, (__bf16)v.w };
        ((bf16x4*)o0)[i] = r;
    } else if (i < 2 * nvec) {
        int j = i - nvec;
        float4 v = ((const float4*)g1)[j];
        bf16x4 r = { (__bf16)v.x, (__bf16)v.y, (__bf16)v.z, (__bf16)v.w };
        ((bf16x4*)o1)[j] = r;
    } else {
        int j = i - 2 * nvec;
        if (j < 4096) {
            // fc_w1 is [in 64][out 64]; store transposed [out][in] bf16
            w1t[(j & 63) * 64 + (j >> 6)] = (__bf16)w1f[j];
        } else if (j < 4096 + 1024) {
            int k = j - 4096;
            w2t[(k & 15) * 64 + (k >> 4)] = (__bf16)w2f[k];
        }
    }
}

// 64 points per wave, lane = point.
// fc1: D[out64][pt64] = W1[out][k] * X[pt][k]^T -> 32 MFMAs; fc2: 8 MFMAs.
// BF16G path: W1/W2 MFMA A-fragments come straight from a pre-transposed
// bf16 workspace copy (register-resident, L1/L2-cached) -> LDS holds only
// the per-wave X tiles (32KB + biases) -> 4 blocks/CU instead of 3.
// X tile is [pt][64 feats] with 128B rows + XOR swizzle (swzb) -> all
// ds_read_b128 / ds_write ops conflict-free.
template<bool BF16G>
__global__ __launch_bounds__(256, BF16G ? 4 : 3) void gridnet_fwd(
    const float2* __restrict__ pos, const float2* __restrict__ dir_,
    const float* __restrict__ pos_gridf, const float* __restrict__ dir_gridf,
    const __bf16* __restrict__ pos_gridb, const __bf16* __restrict__ dir_gridb,
    const __bf16* __restrict__ W1t, const __bf16* __restrict__ W2t,
    const float* __restrict__ enc_w1, const float* __restrict__ enc_b1,
    const float* __restrict__ enc_w2, const float* __restrict__ enc_b2,
    const float* __restrict__ fc_w1, const float* __restrict__ fc_b1,
    const float* __restrict__ fc_w2, const float* __restrict__ fc_b2,
    const float* __restrict__ fc_w3, const float* __restrict__ fc_b3,
    const float* __restrict__ fc_w4, const float* __restrict__ fc_b4,
    float* __restrict__ out, int n)
{
    constexpr int XBYTES = 4 * 64 * 128;   // 4 waves x [64 pt][128B]
    __shared__ __align__(16) char smem[BF16G ? XBYTES : XBYTES + 64 * 128 + 16 * 128];
    __shared__ float b1lds[64];
    __shared__ float b2lds[16];

    const int tid  = threadIdx.x;
    const int lane = tid & 63;
    const int wid  = tid >> 6;
    const int quad = lane >> 4;
    const int l15  = lane & 15;

    char* Xw = smem + wid * 64 * 128;
    char* W1p = smem + XBYTES;      // fallback (fp32 grids) only
    char* W2p = W1p + 64 * 128;

    if (!BF16G) {
        for (int idx = tid; idx < 4096; idx += 256)
            *(__bf16*)(W1p + swzb(idx & 63, (idx >> 6) * 2)) = (__bf16)fc_w1[idx];
        for (int idx = tid; idx < 1024; idx += 256)
            *(__bf16*)(W2p + swzb(idx & 15, (idx >> 4) * 2)) = (__bf16)fc_w2[idx];
    }
    if (tid < 64) b1lds[tid] = fc_b1[tid];
    if (tid < 16) b2lds[tid] = fc_b2[tid];
    __syncthreads();

    int i  = blockIdx.x * 256 + wid * 64 + lane;
    int ic = min(i, n - 1);

    // ---- encoders for both passes up front ----
    int   ctl[2], ctr[2], cbl[2], cbr[2];
    float wtl[2], wtr[2], wbl[2], wbr[2];
    #pragma unroll
    for (int pass = 0; pass < 2; ++pass) {
        float2 xy = pass ? dir_[ic] : pos[ic];
        float hh[4];
        #pragma unroll
        for (int k = 0; k < 4; ++k)
            hh[k] = fast_tanh(xy.x * enc_w1[k] + xy.y * enc_w1[4 + k] + enc_b1[k]);
        float e0 = enc_b2[0], e1 = enc_b2[1];
        #pragma unroll
        for (int k = 0; k < 4; ++k) {
            e0 += hh[k] * enc_w2[3 * k + 0];
            e1 += hh[k] * enc_w2[3 * k + 1];
        }
        float x = sigmoidf_(e0) * 255.0f;
        float y = sigmoidf_(e1) * 255.0f;
        int x0 = (int)x, y0 = (int)y;
        float xf = x - (float)x0, yf = y - (float)y0;
        int x1 = min(x0 + 1, 255), y1 = min(y0 + 1, 255);
        float oxf = 1.0f - xf, oyf = 1.0f - yf;
        wtl[pass] = oyf * oxf; wtr[pass] = oyf * xf;
        wbl[pass] = yf * oxf;  wbr[pass] = yf * xf;
        ctl[pass] = ((y0 << 8) + x0) << 5; ctr[pass] = ((y0 << 8) + x1) << 5;
        cbl[pass] = ((y1 << 8) + x0) << 5; cbr[pass] = ((y1 << 8) + x1) << 5;
    }

    // ---- gather + blend; all 16 chunk loads of a pass issued before blending ----
    #pragma unroll
    for (int pass = 0; pass < 2; ++pass) {
        if (BF16G) {
            const __bf16* g = pass ? dir_gridb : pos_gridb;
            bf16x8 A[4], B[4], C[4], D[4];
            #pragma unroll
            for (int c = 0; c < 4; ++c) A[c] = *(const bf16x8*)(g + ctl[pass] + c * 8);
            #pragma unroll
            for (int c = 0; c < 4; ++c) B[c] = *(const bf16x8*)(g + ctr[pass] + c * 8);
            #pragma unroll
            for (int c = 0; c < 4; ++c) C[c] = *(const bf16x8*)(g + cbl[pass] + c * 8);
            #pragma unroll
            for (int c = 0; c < 4; ++c) D[c] = *(const bf16x8*)(g + cbr[pass] + c * 8);
            #pragma unroll
            for (int c = 0; c < 4; ++c) {
                floatx8 r = wtl[pass] * __builtin_convertvector(A[c], floatx8)
                          + wtr[pass] * __builtin_convertvector(B[c], floatx8)
                          + wbl[pass] * __builtin_convertvector(C[c], floatx8)
                          + wbr[pass] * __builtin_convertvector(D[c], floatx8);
                *(bf16x8*)(Xw + swzb(lane, pass * 64 + c * 16)) = __builtin_convertvector(r, bf16x8);
            }
        } else {
            const float* g = pass ? dir_gridf : pos_gridf;
            #pragma unroll
            for (int c = 0; c < 4; ++c) {
                floatx8 fa = *(const floatx8*)(g + ctl[pass] + c * 8);
                floatx8 fb = *(const floatx8*)(g + ctr[pass] + c * 8);
                floatx8 fc = *(const floatx8*)(g + cbl[pass] + c * 8);
                floatx8 fd = *(const floatx8*)(g + cbr[pass] + c * 8);
                floatx8 r = wtl[pass] * fa + wtr[pass] * fb + wbl[pass] * fc + wbr[pass] * fd;
                *(bf16x8*)(Xw + swzb(lane, pass * 64 + c * 16)) = __builtin_convertvector(r, bf16x8);
            }
        }
    }

    __asm__ volatile("s_waitcnt lgkmcnt(0)" ::: "memory");

    // ---- W1 fragments into registers (BF16G: straight from workspace) ----
    bf16x8 wf[2][4];
    #pragma unroll
    for (int ks = 0; ks < 2; ++ks)
        #pragma unroll
        for (int mt = 0; mt < 4; ++mt) {
            if (BF16G)
                wf[ks][mt] = *(const bf16x8*)(W1t + (mt * 16 + l15) * 64 + ks * 32 + quad * 8);
            else
                wf[ks][mt] = *(const bf16x8*)(W1p + swzb(mt * 16 + l15, ks * 64 + quad * 16));
        }

    floatx4 b1v[4];
    #pragma unroll
    for (int mt = 0; mt < 4; ++mt)
        b1v[mt] = *(const floatx4*)(b1lds + mt * 16 + quad * 4);

    // ---- fc1: D[out 64][pt 64] = W1 * X^T : 32 MFMAs ----
    floatx4 acc[4][4];
    #pragma unroll
    for (int mt = 0; mt < 4; ++mt)
        #pragma unroll
        for (int nt = 0; nt < 4; ++nt)
            acc[mt][nt] = b1v[mt];

    #pragma unroll
    for (int ks = 0; ks < 2; ++ks) {
        bf16x8 xf[4];
        #pragma unroll
        for (int nt = 0; nt < 4; ++nt)
            xf[nt] = *(const bf16x8*)(Xw + swzb(nt * 16 + l15, ks * 64 + quad * 16));
        #pragma unroll
        for (int mt = 0; mt < 4; ++mt)
            #pragma unroll
            for (int nt = 0; nt < 4; ++nt)
                acc[mt][nt] = __builtin_amdgcn_mfma_f32_16x16x32_bf16(wf[ks][mt], xf[nt], acc[mt][nt], 0, 0, 0);
    }

    // writeback h1: lane holds feats (mt*16+quad*4 .. +3) of pt (nt*16+l15) -> b64 stores
    #pragma unroll
    for (int mt = 0; mt < 4; ++mt)
        #pragma unroll
        for (int nt = 0; nt < 4; ++nt) {
            bf16x4 hv;
            #pragma unroll
            for (int r = 0; r < 4; ++r)
                hv[r] = (__bf16)leaky(acc[mt][nt][r]);
            *(bf16x4*)(Xw + swzb(nt * 16 + l15, mt * 32 + quad * 8)) = hv;
        }
    __asm__ volatile("s_waitcnt lgkmcnt(0)" ::: "memory");

    // ---- fc2: D[out 16][pt 64] : 8 MFMAs ----
    bf16x8 w2f[2];
    #pragma unroll
    for (int ks = 0; ks < 2; ++ks) {
        if (BF16G)
            w2f[ks] = *(const bf16x8*)(W2t + l15 * 64 + ks * 32 + quad * 8);
        else
            w2f[ks] = *(const bf16x8*)(W2p + swzb(l15, ks * 64 + quad * 16));
    }
    floatx4 b2v = *(const floatx4*)(b2lds + quad * 4);
    floatx4 acc2[4];
    #pragma unroll
    for (int nt = 0; nt < 4; ++nt) acc2[nt] = b2v;
    #pragma unroll
    for (int ks = 0; ks < 2; ++ks) {
        #pragma unroll
        for (int nt = 0; nt < 4; ++nt) {
            bf16x8 hf = *(const bf16x8*)(Xw + swzb(nt * 16 + l15, ks * 64 + quad * 16));
            acc2[nt] = __builtin_amdgcn_mfma_f32_16x16x32_bf16(w2f[ks], hf, acc2[nt], 0, 0, 0);
        }
    }

    // writeback h2 fp32: [pt][16 f32] packed at swizzled 16B slots -> b128 stores
    #pragma unroll
    for (int nt = 0; nt < 4; ++nt) {
        floatx4 hv;
        #pragma unroll
        for (int r = 0; r < 4; ++r)
            hv[r] = leaky(acc2[nt][r]);
        *(floatx4*)(Xw + swzb(nt * 16 + l15, quad * 16)) = hv;
    }
    __asm__ volatile("s_waitcnt lgkmcnt(0)" ::: "memory");

    // ---- fc3/fc4 per lane (lane = point), sigmoid, store ----
    float h2[16];
    #pragma unroll
    for (int c = 0; c < 4; ++c) {
        floatx4 v = *(const floatx4*)(Xw + swzb(lane, c * 16));
        h2[4 * c + 0] = v[0]; h2[4 * c + 1] = v[1]; h2[4 * c + 2] = v[2]; h2[4 * c + 3] = v[3];
    }
    float h3[8];
    #pragma unroll
    for (int j = 0; j < 8; ++j) h3[j] = fc_b3[j];
    #pragma unroll
    for (int k = 0; k < 16; ++k) {
        float xv = h2[k];
        #pragma unroll
        for (int j = 0; j < 8; ++j) h3[j] = fmaf(xv, fc_w3[(k << 3) + j], h3[j]);
    }
    #pragma unroll
    for (int j = 0; j < 8; ++j) h3[j] = leaky(h3[j]);

    float o[3];
    #pragma unroll
    for (int j = 0; j < 3; ++j) o[j] = fc_b4[j];
    #pragma unroll
    for (int k = 0; k < 8; ++k) {
        float xv = h3[k];
        #pragma unroll
        for (int j = 0; j < 3; ++j) o[j] = fmaf(xv, fc_w4[3 * k + j], o[j]);
    }
    if (i < n) {
        #pragma unroll
        for (int j = 0; j < 3; ++j)
            out[3 * i + j] = sigmoidf_(leaky(o[j])) * 255.0f;
    }
}

extern "C" void kernel_launch(void* const* d_in, const int* in_sizes, int n_in,
                              void* d_out, int out_size, void* d_ws, size_t ws_size,
                              hipStream_t stream) {
    int n = in_sizes[0] / 2;  // pos is [N,2]
    const int GELEMS = 256 * 256 * 32;
    const int WELEMS = 4096 + 1024;
    bool use_bf16 = ws_size >= (size_t)((2 * GELEMS + WELEMS) * sizeof(__bf16));
    __bf16* g0  = (__bf16*)d_ws;
    __bf16* g1  = g0 + GELEMS;
    __bf16* w1t = g1 + GELEMS;
    __bf16* w2t = w1t + 4096;

    if (use_bf16) {
        int total = 2 * (GELEMS / 4) + WELEMS;
        convert_grids<<<(total + 255) / 256, 256, 0, stream>>>(
            (const float*)d_in[2], (const float*)d_in[3],
            (const float*)d_in[8], (const float*)d_in[10],
            g0, g1, w1t, w2t, GELEMS);
    }

    int blocks = (n + 255) / 256;
    if (use_bf16) {
        gridnet_fwd<true><<<blocks, 256, 0, stream>>>(
            (const float2*)d_in[0], (const float2*)d_in[1],
            (const float*)d_in[2], (const float*)d_in[3], g0, g1, w1t, w2t,
            (const float*)d_in[4], (const float*)d_in[5],
            (const float*)d_in[6], (const float*)d_in[7],
            (const float*)d_in[8], (const float*)d_in[9],
            (const float*)d_in[10], (const float*)d_in[11],
            (const float*)d_in[12], (const float*)d_in[13],
            (const float*)d_in[14], (const float*)d_in[15],
            (float*)d_out, n);
    } else {
        gridnet_fwd<false><<<blocks, 256, 0, stream>>>(
            (const float2*)d_in[0], (const float2*)d_in[1],
            (const float*)d_in[2], (const float*)d_in[3], g0, g1, w1t, w2t,
            (const float*)d_in[4], (const float*)d_in[5],
            (const float*)d_in[6], (const float*)d_in[7],
            (const float*)d_in[8], (const float*)d_in[9],
            (const float*)d_in[10], (const float*)d_in[11],
            (const float*)d_in[12], (const float*)d_in[13],
            (const float*)d_in[14], (const float*)d_in[15],
            (float*)d_out, n);
    }
}